// Round 15
// baseline (487.294 us; speedup 1.0000x reference)
//
#include <hip/hip_runtime.h>

// LinearAttention fp32 [4,16,4096,64]: out = (Q' (K'^T V)) / (Q'.k_sum + eps), X' = elu(X)+1.
// R15 = R13 (NPB=32; R14's NPB=64 regressed: +68MB partial/reduce traffic = +10us)
//  + reduce fused into pass 1 via last-block pattern (threadfence + per-bh atomic
//    ticket; winner re-reduces 32 partials in its dead LDS)
//  + winner writes the aggregate PRE-PACKED in out_kernel's bf16 kvT layout
//    (+fp32 ksum): out reads 8.5KB/block instead of 16.6KB and skips packing.
// Pass 1 (kv_mfma_fused): NT loads, single-phase, bf16 MFMA, partial -> ticket -> pack.
// Pass 2 (out_kernel): Q' bf16 staged, kvT copied linearly, 16x MFMA, fp32 denom,
//   barriered LDS repack -> coalesced NT stores. Tail identical to R13.

#define EPS_LA 1e-6f

constexpr int BH = 64;
constexpr int SEQ = 4096;
constexpr int DIM = 64;
constexpr int KVELEM = DIM * DIM + DIM;  // 4160 (fp32 partial: kv[64][64] + ksum[64])
constexpr int NPB = 32;                  // partial blocks per bh
constexpr int SCH = SEQ / NPB;           // 128 s-rows per block
constexpr int KVO = 2048 + 64;           // packed fin dwords/bh: kvT bf16-pairs + fp32 ksum

typedef short bf16x8 __attribute__((ext_vector_type(8)));
typedef float f32x4 __attribute__((ext_vector_type(4)));

__device__ __forceinline__ float elu1(float x) {
    return x > 0.f ? x + 1.f : __expf(x);
}
__device__ __forceinline__ f32x4 elu4v(f32x4 v) {
    v[0] = elu1(v[0]); v[1] = elu1(v[1]); v[2] = elu1(v[2]); v[3] = elu1(v[3]);
    return v;
}
__device__ __forceinline__ f32x4 ntld(const float* p) {
    return __builtin_nontemporal_load((const f32x4*)p);
}

// fp32 -> bf16 (RNE; inputs finite)
__device__ __forceinline__ unsigned int f2bf(float x) {
    unsigned int u = __float_as_uint(x);
    return (u + 0x7fffu + ((u >> 16) & 1u)) >> 16;
}
__device__ __forceinline__ unsigned int pack2bf(float lo, float hi) {
    return f2bf(lo) | (f2bf(hi) << 16);
}

// Pass-1 LDS swizzle: dword index into [64 rows][64 dword-cols]
__device__ __forceinline__ int swz(int d, int s2) {
    return d * 64 + (s2 ^ ((((d >> 1) ^ (d >> 2)) & 7) << 2));
}

// Pack fp32 aggregate (red[4160]: kv d-major + ksum) -> out_kernel's fin layout.
__device__ __forceinline__ void pack_fin(const float* red, unsigned int* f, int t) {
    #pragma unroll
    for (int i = 0; i < 2; ++i) {
        const int p = (t >> 4) + 16 * i;      // d-pair 0..31
        const int e0 = (t & 15) * 4;
        const f32x4 a = *(const f32x4*)&red[(size_t)(2 * p) * DIM + e0];
        const f32x4 b = *(const f32x4*)&red[(size_t)(2 * p + 1) * DIM + e0];
        #pragma unroll
        for (int j = 0; j < 4; ++j) {
            const int e = e0 + j;
            f[e * 32 + (p ^ ((e & 7) << 2))] = pack2bf(a[j], b[j]);
        }
    }
    if (t < 64) ((float*)f)[2048 + t] = red[DIM * DIM + t];  // fp32 ksum
}

template<bool FUSED>
__global__ __launch_bounds__(256, 4) void kv_mfma_kernel(
    const float* __restrict__ K, const float* __restrict__ V,
    float* __restrict__ partial, float* __restrict__ finp,
    unsigned int* __restrict__ counters) {
    const int bh = blockIdx.y;
    const int blk = blockIdx.x;
    const int t = threadIdx.x;
    const int w = t >> 6, l = t & 63;

    __shared__ unsigned int ldsb[2 * 64 * 64 + 256];  // KT | VT | csum
    __shared__ int lastFlag;
    unsigned int* KT = ldsb;
    unsigned int* VT = ldsb + 4096;
    float* csumS = (float*)(ldsb + 8192);  // [4][64]

    const float* Kb = K + ((size_t)bh * SEQ + (size_t)blk * SCH) * DIM;
    const float* Vb = V + ((size_t)bh * SEQ + (size_t)blk * SCH) * DIM;

    const int c0 = (t & 15) * 4;  // staged col base (d rows c0..c0+3)
    const int pg = t >> 4;        // s-pair group base: pairs pg + 16*i
    const int lg = l >> 4;        // MFMA k-slice group 0..3
    const int lr = l & 15;        // MFMA row/col within tile

    // ---- issue ALL 16 non-temporal loads ----
    f32x4 kf[8], vf[8];
    #pragma unroll
    for (int i = 0; i < 4; ++i) {
        const int p = pg + 16 * i;
        kf[2 * i]     = ntld(Kb + (size_t)(2 * p) * DIM + c0);
        kf[2 * i + 1] = ntld(Kb + (size_t)(2 * p + 1) * DIM + c0);
    }
    #pragma unroll
    for (int i = 0; i < 4; ++i) {
        const int p = pg + 16 * i;
        vf[2 * i]     = ntld(Vb + (size_t)(2 * p) * DIM + c0);
        vf[2 * i + 1] = ntld(Vb + (size_t)(2 * p + 1) * DIM + c0);
    }

    // ---- elu + pack + transpose into LDS ----
    float cs0 = 0.f, cs1 = 0.f, cs2 = 0.f, cs3 = 0.f;
    #pragma unroll
    for (int i = 0; i < 4; ++i) {
        const int p = pg + 16 * i;
        const f32x4 ka = elu4v(kf[2 * i]);
        const f32x4 kb = elu4v(kf[2 * i + 1]);
        cs0 += ka[0] + kb[0]; cs1 += ka[1] + kb[1];
        cs2 += ka[2] + kb[2]; cs3 += ka[3] + kb[3];
        KT[swz(c0 + 0, p)] = pack2bf(ka[0], kb[0]);
        KT[swz(c0 + 1, p)] = pack2bf(ka[1], kb[1]);
        KT[swz(c0 + 2, p)] = pack2bf(ka[2], kb[2]);
        KT[swz(c0 + 3, p)] = pack2bf(ka[3], kb[3]);
        const f32x4 va = vf[2 * i], vb = vf[2 * i + 1];
        VT[swz(c0 + 0, p)] = pack2bf(va[0], vb[0]);
        VT[swz(c0 + 1, p)] = pack2bf(va[1], vb[1]);
        VT[swz(c0 + 2, p)] = pack2bf(va[2], vb[2]);
        VT[swz(c0 + 3, p)] = pack2bf(va[3], vb[3]);
    }

    // fold column sums across 16-lane groups (lanes l, l^16, l^32, l^48 share c0)
    cs0 += __shfl_xor(cs0, 16); cs0 += __shfl_xor(cs0, 32);
    cs1 += __shfl_xor(cs1, 16); cs1 += __shfl_xor(cs1, 32);
    cs2 += __shfl_xor(cs2, 16); cs2 += __shfl_xor(cs2, 32);
    cs3 += __shfl_xor(cs3, 16); cs3 += __shfl_xor(cs3, 32);
    if (l < 16) *(f32x4*)&csumS[w * 64 + l * 4] = f32x4{cs0, cs1, cs2, cs3};

    __syncthreads();

    // ---- MFMA: wave w owns e-cols [16w,16w+16); K=128 (4 steps of 32) ----
    f32x4 acc[4];
    #pragma unroll
    for (int m = 0; m < 4; ++m)
        #pragma unroll
        for (int r = 0; r < 4; ++r) acc[m][r] = 0.f;

    #pragma unroll
    for (int ks = 0; ks < 4; ++ks) {
        const int s2b = ks * 16 + lg * 4;
        const bf16x8 bfrag =
            *reinterpret_cast<const bf16x8*>(&VT[swz(16 * w + lr, s2b)]);
        #pragma unroll
        for (int m = 0; m < 4; ++m) {
            const bf16x8 afrag =
                *reinterpret_cast<const bf16x8*>(&KT[swz(16 * m + lr, s2b)]);
            acc[m] = __builtin_amdgcn_mfma_f32_16x16x32_bf16(afrag, bfrag, acc[m],
                                                             0, 0, 0);
        }
    }

    if (!FUSED) {
        // atomic fallback: accumulate directly into fp32 aggregate `partial`
        float* wout = partial + (size_t)bh * KVELEM;
        if (t < 64) {
            const float s = csumS[0 * 64 + t] + csumS[1 * 64 + t] +
                            csumS[2 * 64 + t] + csumS[3 * 64 + t];
            atomicAdd(&wout[DIM * DIM + t], s);
        }
        #pragma unroll
        for (int m = 0; m < 4; ++m)
            #pragma unroll
            for (int r = 0; r < 4; ++r)
                atomicAdd(&wout[(size_t)(16 * m + 4 * lg + r) * DIM + 16 * w + lr],
                          acc[m][r]);
        return;
    }

    // ---- store this block's fp32 partial ----
    float* wout = partial + ((size_t)blk * BH + bh) * KVELEM;
    if (t < 64) {
        wout[DIM * DIM + t] = csumS[0 * 64 + t] + csumS[1 * 64 + t] +
                              csumS[2 * 64 + t] + csumS[3 * 64 + t];
    }
    #pragma unroll
    for (int m = 0; m < 4; ++m)
        #pragma unroll
        for (int r = 0; r < 4; ++r)
            wout[(size_t)(16 * m + 4 * lg + r) * DIM + 16 * w + lr] = acc[m][r];

    // ---- last-block ticket: winner reduces all NPB partials and packs fin ----
    __threadfence();  // release: this block's partial visible device-wide
    if (t == 0) lastFlag = (atomicAdd(&counters[bh], 1u) == NPB - 1);
    __syncthreads();
    if (!lastFlag) return;
    __threadfence();  // acquire: see all other blocks' partials

    float* red = (float*)ldsb;  // 4160 floats; KT/VT fully consumed above
    #pragma unroll
    for (int i = 0; i < 5; ++i) {
        const int j4 = t + 256 * i;  // f32x4 slot 0..1039
        if (j4 < KVELEM / 4) {
            f32x4 s = {0.f, 0.f, 0.f, 0.f};
            #pragma unroll 4
            for (int c = 0; c < NPB; ++c)
                s += *(const f32x4*)&partial[((size_t)c * BH + bh) * KVELEM + j4 * 4];
            *(f32x4*)&red[j4 * 4] = s;
        }
    }
    __syncthreads();
    pack_fin(red, (unsigned int*)(finp + (size_t)bh * KVO), t);
}

// Fallback pack: fp32 aggregate -> packed fin (one block per bh)
__global__ __launch_bounds__(256) void pack_kernel(
    const float* __restrict__ fin, float* __restrict__ finp) {
    const int bh = blockIdx.y;
    const int t = threadIdx.x;
    __shared__ float red[KVELEM];
    #pragma unroll
    for (int i = 0; i < 5; ++i) {
        const int j4 = t + 256 * i;
        if (j4 < KVELEM / 4)
            *(f32x4*)&red[j4 * 4] =
                *(const f32x4*)&fin[(size_t)bh * KVELEM + j4 * 4];
    }
    __syncthreads();
    pack_fin(red, (unsigned int*)(finp + (size_t)bh * KVO), t);
}

// Pass 2 (MFMA): block = 256 thr (4 waves); wave wv owns 32 q-rows.
// kvT copied linearly from packed fin; fp32 denom via shfl butterfly;
// acc repacked through per-wave LDS (barriered) -> coalesced NT f32x4 stores.
__global__ __launch_bounds__(256) void out_kernel(
    const float* __restrict__ Q, const float* __restrict__ finp,
    float* __restrict__ out) {
    const int bh = blockIdx.y;
    const int rb = blockIdx.x;  // 128-row block
    const int t = threadIdx.x;
    const int wv = t >> 6, l = t & 63;
    const int lr = l & 15, lg = l >> 4;

    __shared__ unsigned int qA[4 * 32 * 32];  // 16 KB: per-wave Q' bf16 [row][d-pair]
    __shared__ unsigned int kvT[64 * 32];     // 8 KB: kv^T bf16 (pre-packed layout)
    __shared__ float denomS[128];

    const unsigned int* fT = (const unsigned int*)(finp + (size_t)bh * KVO);
    const float* ksumF = (const float*)(fT + 2048);
    const float* Qb = Q + ((size_t)bh * SEQ + (size_t)rb * 128) * DIM;
    float* Ob = out + ((size_t)bh * SEQ + (size_t)rb * 128) * DIM;

    // ---- kvT staging: straight copy (already packed+swizzled by producer) ----
    #pragma unroll
    for (int i = 0; i < 2; ++i) {
        const int j4 = t + 256 * i;  // uint4 slot 0..511
        *(uint4*)&kvT[j4 * 4] = *(const uint4*)&fT[j4 * 4];
    }

    // ---- q staging (NT): elu, pack bf16, swizzle; fp32 denom partials ----
    const int c0 = lr * 4;
    const f32x4 ks4 = *(const f32x4*)(ksumF + c0);  // fp32 ksum slice (hot)
    float pd[8];
    #pragma unroll
    for (int it = 0; it < 8; ++it) {
        const int row = it * 4 + lg;          // 0..31 within wave
        const f32x4 qv = elu4v(ntld(Qb + (size_t)(wv * 32 + row) * DIM + c0));
        pd[it] = qv[0] * ks4[0] + qv[1] * ks4[1] + qv[2] * ks4[2] + qv[3] * ks4[3];
        uint2 val;
        val.x = pack2bf(qv[0], qv[1]);
        val.y = pack2bf(qv[2], qv[3]);
        *(uint2*)&qA[wv * 1024 + row * 32 + ((2 * lr) ^ ((row & 7) << 2))] = val;
    }
    // butterfly over the 16-lane (lr) group -> full denom per row
    #pragma unroll
    for (int it = 0; it < 8; ++it) {
        float v = pd[it];
        v += __shfl_xor(v, 1); v += __shfl_xor(v, 2);
        v += __shfl_xor(v, 4); v += __shfl_xor(v, 8);
        if (lr == 0) denomS[wv * 32 + it * 4 + lg] = v + EPS_LA;
    }
    __syncthreads();

    // ---- MFMA: rows 16*mt+lr, cols 16*nt+lr, K=64 in 2 steps ----
    f32x4 acc[2][4];
    #pragma unroll
    for (int mt = 0; mt < 2; ++mt)
        #pragma unroll
        for (int nt = 0; nt < 4; ++nt)
            #pragma unroll
            for (int r = 0; r < 4; ++r) acc[mt][nt][r] = 0.f;

    #pragma unroll
    for (int ks = 0; ks < 2; ++ks) {
        const int kd = 4 * lg + 16 * ks;      // dword base of the lane's k-slice
        const int am = (lr & 7) << 2;
        const bf16x8 a0 = *(const bf16x8*)&qA[wv * 1024 + lr * 32 + (kd ^ am)];
        const bf16x8 a1 = *(const bf16x8*)&qA[wv * 1024 + (16 + lr) * 32 + (kd ^ am)];
        #pragma unroll
        for (int nt = 0; nt < 4; ++nt) {
            const bf16x8 b =
                *(const bf16x8*)&kvT[(16 * nt + lr) * 32 + (kd ^ am)];
            acc[0][nt] = __builtin_amdgcn_mfma_f32_16x16x32_bf16(a0, b, acc[0][nt],
                                                                 0, 0, 0);
            acc[1][nt] = __builtin_amdgcn_mfma_f32_16x16x32_bf16(a1, b, acc[1][nt],
                                                                 0, 0, 0);
        }
    }

    // ---- repack acc through per-wave LDS -> coalesced NT stores (barriered) ----
    float* oS = (float*)qA;  // per-wave 1024-float region at wv*1024
    #pragma unroll
    for (int mt = 0; mt < 2; ++mt) {
        __syncthreads();  // qA bf16 reads (mt=0) / prior read-back (mt=1) complete
        #pragma unroll
        for (int r = 0; r < 4; ++r) {
            const int row = 4 * lg + r;  // 0..15
            const float inv = 1.f / denomS[wv * 32 + mt * 16 + row];
            #pragma unroll
            for (int nt = 0; nt < 4; ++nt) {
                const int colp = (16 * nt + lr) ^ (lg << 4);
                oS[wv * 1024 + row * 64 + colp] = acc[mt][nt][r] * inv;
            }
        }
        __syncthreads();  // writes visible before read-back
        #pragma unroll
        for (int j = 0; j < 4; ++j) {
            const int row = 4 * j + lg;           // 0..15
            const int cb = lr * 4;
            const int colp = cb ^ ((row >> 2) << 4);
            const f32x4 o = *(const f32x4*)&oS[wv * 1024 + row * 64 + colp];
            float* orow = Ob + (size_t)(wv * 32 + mt * 16 + row) * DIM + cb;
            __builtin_nontemporal_store(o, (f32x4*)orow);
        }
    }
}

extern "C" void kernel_launch(void* const* d_in, const int* in_sizes, int n_in,
                              void* d_out, int out_size, void* d_ws, size_t ws_size,
                              hipStream_t stream) {
    const float* q = (const float*)d_in[0];
    const float* k = (const float*)d_in[1];
    const float* v = (const float*)d_in[2];
    float* out = (float*)d_out;
    float* ws = (float*)d_ws;

    const size_t partial_elems = (size_t)NPB * BH * KVELEM;
    const size_t finp_elems = (size_t)BH * KVO;
    const size_t need = (partial_elems + finp_elems + 64) * sizeof(float);

    dim3 blk(256);
    if (ws_size >= need) {
        float* partial = ws;
        float* finp = ws + partial_elems;
        unsigned int* counters = (unsigned int*)(finp + finp_elems);
        hipMemsetAsync(counters, 0, 64 * sizeof(unsigned int), stream);
        hipLaunchKernelGGL((kv_mfma_kernel<true>), dim3(NPB, BH), blk, 0, stream,
                           k, v, partial, finp, counters);
        hipLaunchKernelGGL(out_kernel, dim3(SEQ / 128, BH), blk, 0, stream,
                           q, finp, out);
    } else {
        // fallback: atomic accumulation into fp32 aggregate + pack kernel
        float* fin = ws;                          // BH*KVELEM fp32
        float* finp = ws + (size_t)BH * KVELEM;   // BH*KVO dwords
        hipMemsetAsync(fin, 0, (size_t)BH * KVELEM * sizeof(float), stream);
        hipLaunchKernelGGL((kv_mfma_kernel<false>), dim3(NPB, BH), blk, 0, stream,
                           k, v, fin, finp, (unsigned int*)nullptr);
        hipLaunchKernelGGL(pack_kernel, dim3(1, BH), blk, 0, stream, fin, finp);
        hipLaunchKernelGGL(out_kernel, dim3(SEQ / 128, BH), blk, 0, stream,
                           q, finp, out);
    }
}

// Round 16
// 77.857 us; speedup vs baseline: 6.2588x; 6.2588x over previous
//
#include <hip/hip_runtime.h>

// LinearAttention fp32 [4,16,4096,64]: out = (Q' (K'^T V)) / (Q'.k_sum + eps), X' = elu(X)+1.
// R16 = R13 structure (3 kernels; R15's per-block __threadfence serialized the
// device: 480us at 3% HBM — device-scope fences flush non-coherent per-XCD L2s,
// NEVER put them in the per-block path) + R15's pre-packed aggregate, now produced
// by the reduce kernel (launch boundary provides ordering, no fence needed):
//   reduce folds 32 partials in LDS and emits kvT bf16-swizzled + fp32 ksum;
//   out_kernel copies kvT linearly (8.5KB vs 16.6KB) and skips packing math.
// Pass 1 (kv_mfma): NT loads, single-phase, bf16 MFMA (K=128), 4 blocks/CU.
// Pass 2 (out_kernel): Q' bf16 staged, 16x MFMA, fp32 denom, barriered LDS repack,
//   coalesced NT stores.

#define EPS_LA 1e-6f

constexpr int BH = 64;
constexpr int SEQ = 4096;
constexpr int DIM = 64;
constexpr int KVELEM = DIM * DIM + DIM;  // 4160 fp32 (partial: kv + ksum)
constexpr int NPB = 32;                  // partial blocks per bh
constexpr int SCH = SEQ / NPB;           // 128 s-rows per block
constexpr int KVO = 2048 + 64;           // packed dwords/bh: bf16 kvT pairs + fp32 ksum

typedef short bf16x8 __attribute__((ext_vector_type(8)));
typedef float f32x4 __attribute__((ext_vector_type(4)));

__device__ __forceinline__ float elu1(float x) {
    return x > 0.f ? x + 1.f : __expf(x);
}
__device__ __forceinline__ f32x4 elu4v(f32x4 v) {
    v[0] = elu1(v[0]); v[1] = elu1(v[1]); v[2] = elu1(v[2]); v[3] = elu1(v[3]);
    return v;
}
__device__ __forceinline__ f32x4 ntld(const float* p) {
    return __builtin_nontemporal_load((const f32x4*)p);
}

// fp32 -> bf16 (RNE; inputs finite)
__device__ __forceinline__ unsigned int f2bf(float x) {
    unsigned int u = __float_as_uint(x);
    return (u + 0x7fffu + ((u >> 16) & 1u)) >> 16;
}
__device__ __forceinline__ unsigned int pack2bf(float lo, float hi) {
    return f2bf(lo) | (f2bf(hi) << 16);
}

// Pass-1 LDS swizzle: dword index into [64 rows][64 dword-cols]
__device__ __forceinline__ int swz(int d, int s2) {
    return d * 64 + (s2 ^ ((((d >> 1) ^ (d >> 2)) & 7) << 2));
}

// Pack fp32 aggregate red[4160] (kv d-major + ksum) -> out_kernel's layout:
// dword e*32 + (p ^ ((e&7)<<2)) = bf16 pair (kv[2p][e], kv[2p+1][e]); +fp32 ksum.
__device__ __forceinline__ void pack_fin(const float* red, unsigned int* f, int t) {
    #pragma unroll
    for (int i = 0; i < 2; ++i) {
        const int p = (t >> 4) + 16 * i;      // d-pair 0..31
        const int e0 = (t & 15) * 4;
        const f32x4 a = *(const f32x4*)&red[(size_t)(2 * p) * DIM + e0];
        const f32x4 b = *(const f32x4*)&red[(size_t)(2 * p + 1) * DIM + e0];
        #pragma unroll
        for (int j = 0; j < 4; ++j) {
            const int e = e0 + j;
            f[e * 32 + (p ^ ((e & 7) << 2))] = pack2bf(a[j], b[j]);
        }
    }
    if (t < 64) ((float*)f)[2048 + t] = red[DIM * DIM + t];
}

template<bool ATOMIC>
__global__ __launch_bounds__(256, 4) void kv_mfma_kernel(
    const float* __restrict__ K, const float* __restrict__ V,
    float* __restrict__ dst) {
    const int bh = blockIdx.y;
    const int blk = blockIdx.x;
    const int t = threadIdx.x;
    const int w = t >> 6, l = t & 63;

    __shared__ unsigned int KT[64 * 64];  // 16 KB
    __shared__ unsigned int VT[64 * 64];  // 16 KB
    __shared__ float csumS[4][64];        // 1 KB

    const float* Kb = K + ((size_t)bh * SEQ + (size_t)blk * SCH) * DIM;
    const float* Vb = V + ((size_t)bh * SEQ + (size_t)blk * SCH) * DIM;

    const int c0 = (t & 15) * 4;
    const int pg = t >> 4;
    const int lg = l >> 4;
    const int lr = l & 15;

    // ---- issue ALL 16 non-temporal loads ----
    f32x4 kf[8], vf[8];
    #pragma unroll
    for (int i = 0; i < 4; ++i) {
        const int p = pg + 16 * i;
        kf[2 * i]     = ntld(Kb + (size_t)(2 * p) * DIM + c0);
        kf[2 * i + 1] = ntld(Kb + (size_t)(2 * p + 1) * DIM + c0);
    }
    #pragma unroll
    for (int i = 0; i < 4; ++i) {
        const int p = pg + 16 * i;
        vf[2 * i]     = ntld(Vb + (size_t)(2 * p) * DIM + c0);
        vf[2 * i + 1] = ntld(Vb + (size_t)(2 * p + 1) * DIM + c0);
    }

    // ---- elu + pack + transpose into LDS ----
    float cs0 = 0.f, cs1 = 0.f, cs2 = 0.f, cs3 = 0.f;
    #pragma unroll
    for (int i = 0; i < 4; ++i) {
        const int p = pg + 16 * i;
        const f32x4 ka = elu4v(kf[2 * i]);
        const f32x4 kb = elu4v(kf[2 * i + 1]);
        cs0 += ka[0] + kb[0]; cs1 += ka[1] + kb[1];
        cs2 += ka[2] + kb[2]; cs3 += ka[3] + kb[3];
        KT[swz(c0 + 0, p)] = pack2bf(ka[0], kb[0]);
        KT[swz(c0 + 1, p)] = pack2bf(ka[1], kb[1]);
        KT[swz(c0 + 2, p)] = pack2bf(ka[2], kb[2]);
        KT[swz(c0 + 3, p)] = pack2bf(ka[3], kb[3]);
        const f32x4 va = vf[2 * i], vb = vf[2 * i + 1];
        VT[swz(c0 + 0, p)] = pack2bf(va[0], vb[0]);
        VT[swz(c0 + 1, p)] = pack2bf(va[1], vb[1]);
        VT[swz(c0 + 2, p)] = pack2bf(va[2], vb[2]);
        VT[swz(c0 + 3, p)] = pack2bf(va[3], vb[3]);
    }

    cs0 += __shfl_xor(cs0, 16); cs0 += __shfl_xor(cs0, 32);
    cs1 += __shfl_xor(cs1, 16); cs1 += __shfl_xor(cs1, 32);
    cs2 += __shfl_xor(cs2, 16); cs2 += __shfl_xor(cs2, 32);
    cs3 += __shfl_xor(cs3, 16); cs3 += __shfl_xor(cs3, 32);
    if (l < 16) *(f32x4*)&csumS[w][l * 4] = f32x4{cs0, cs1, cs2, cs3};

    __syncthreads();  // the ONLY barrier

    // ---- MFMA: wave w owns e-cols [16w,16w+16); K=128 (4 steps of 32) ----
    f32x4 acc[4];
    #pragma unroll
    for (int m = 0; m < 4; ++m)
        #pragma unroll
        for (int r = 0; r < 4; ++r) acc[m][r] = 0.f;

    #pragma unroll
    for (int ks = 0; ks < 4; ++ks) {
        const int s2b = ks * 16 + lg * 4;
        const bf16x8 bfrag =
            *reinterpret_cast<const bf16x8*>(&VT[swz(16 * w + lr, s2b)]);
        #pragma unroll
        for (int m = 0; m < 4; ++m) {
            const bf16x8 afrag =
                *reinterpret_cast<const bf16x8*>(&KT[swz(16 * m + lr, s2b)]);
            acc[m] = __builtin_amdgcn_mfma_f32_16x16x32_bf16(afrag, bfrag, acc[m],
                                                             0, 0, 0);
        }
    }

    float* wout = ATOMIC ? dst + (size_t)bh * KVELEM
                         : dst + ((size_t)blk * BH + bh) * KVELEM;

    if (t < 64) {
        const float s = csumS[0][t] + csumS[1][t] + csumS[2][t] + csumS[3][t];
        if (ATOMIC) atomicAdd(&wout[DIM * DIM + t], s);
        else        wout[DIM * DIM + t] = s;
    }

    #pragma unroll
    for (int m = 0; m < 4; ++m) {
        #pragma unroll
        for (int r = 0; r < 4; ++r) {
            const int d = 16 * m + 4 * lg + r;
            const int e = 16 * w + lr;
            if (ATOMIC) atomicAdd(&wout[(size_t)d * DIM + e], acc[m][r]);
            else        wout[(size_t)d * DIM + e] = acc[m][r];
        }
    }
}

// Reduce + pack: one block per bh. Fold NPB fp32 partials in LDS, emit packed fin.
__global__ __launch_bounds__(256) void reduce_pack_kernel(
    const float* __restrict__ partial, float* __restrict__ finp) {
    const int bh = blockIdx.x;
    const int t = threadIdx.x;
    __shared__ float red[KVELEM];
    #pragma unroll
    for (int i = 0; i < 5; ++i) {
        const int j4 = t + 256 * i;  // f32x4 slot 0..1039
        if (j4 < KVELEM / 4) {
            f32x4 s = {0.f, 0.f, 0.f, 0.f};
            #pragma unroll 4
            for (int c = 0; c < NPB; ++c)
                s += *(const f32x4*)&partial[((size_t)c * BH + bh) * KVELEM + j4 * 4];
            *(f32x4*)&red[j4 * 4] = s;
        }
    }
    __syncthreads();
    pack_fin(red, (unsigned int*)(finp + (size_t)bh * KVO), t);
}

// Fallback pack (atomic path): fp32 aggregate -> packed fin, one block per bh.
__global__ __launch_bounds__(256) void pack_kernel(
    const float* __restrict__ fin, float* __restrict__ finp) {
    const int bh = blockIdx.x;
    const int t = threadIdx.x;
    __shared__ float red[KVELEM];
    #pragma unroll
    for (int i = 0; i < 5; ++i) {
        const int j4 = t + 256 * i;
        if (j4 < KVELEM / 4)
            *(f32x4*)&red[j4 * 4] = *(const f32x4*)&fin[(size_t)bh * KVELEM + j4 * 4];
    }
    __syncthreads();
    pack_fin(red, (unsigned int*)(finp + (size_t)bh * KVO), t);
}

// Pass 2 (MFMA): block = 256 thr (4 waves); wave wv owns 32 q-rows.
// kvT copied linearly from packed fin; fp32 denom via shfl butterfly;
// acc repacked through per-wave LDS (barriered) -> coalesced NT f32x4 stores.
__global__ __launch_bounds__(256) void out_kernel(
    const float* __restrict__ Q, const float* __restrict__ finp,
    float* __restrict__ out) {
    const int bh = blockIdx.y;
    const int rb = blockIdx.x;  // 128-row block
    const int t = threadIdx.x;
    const int wv = t >> 6, l = t & 63;
    const int lr = l & 15, lg = l >> 4;

    __shared__ unsigned int qA[4 * 32 * 32];  // 16 KB: per-wave Q' bf16 [row][d-pair]
    __shared__ unsigned int kvT[64 * 32];     // 8 KB: kv^T bf16 (pre-packed)
    __shared__ float denomS[128];

    const unsigned int* fT = (const unsigned int*)(finp + (size_t)bh * KVO);
    const float* ksumF = (const float*)(fT + 2048);
    const float* Qb = Q + ((size_t)bh * SEQ + (size_t)rb * 128) * DIM;
    float* Ob = out + ((size_t)bh * SEQ + (size_t)rb * 128) * DIM;

    // ---- kvT staging: straight copy (already packed+swizzled by producer) ----
    #pragma unroll
    for (int i = 0; i < 2; ++i) {
        const int j4 = t + 256 * i;  // uint4 slot 0..511
        *(uint4*)&kvT[j4 * 4] = *(const uint4*)&fT[j4 * 4];
    }

    // ---- q staging (NT): elu, pack bf16, swizzle; fp32 denom partials ----
    const int c0 = lr * 4;
    const f32x4 ks4 = *(const f32x4*)(ksumF + c0);
    float pd[8];
    #pragma unroll
    for (int it = 0; it < 8; ++it) {
        const int row = it * 4 + lg;          // 0..31 within wave
        const f32x4 qv = elu4v(ntld(Qb + (size_t)(wv * 32 + row) * DIM + c0));
        pd[it] = qv[0] * ks4[0] + qv[1] * ks4[1] + qv[2] * ks4[2] + qv[3] * ks4[3];
        uint2 val;
        val.x = pack2bf(qv[0], qv[1]);
        val.y = pack2bf(qv[2], qv[3]);
        *(uint2*)&qA[wv * 1024 + row * 32 + ((2 * lr) ^ ((row & 7) << 2))] = val;
    }
    #pragma unroll
    for (int it = 0; it < 8; ++it) {
        float v = pd[it];
        v += __shfl_xor(v, 1); v += __shfl_xor(v, 2);
        v += __shfl_xor(v, 4); v += __shfl_xor(v, 8);
        if (lr == 0) denomS[wv * 32 + it * 4 + lg] = v + EPS_LA;
    }
    __syncthreads();

    // ---- MFMA: rows 16*mt+lr, cols 16*nt+lr, K=64 in 2 steps ----
    f32x4 acc[2][4];
    #pragma unroll
    for (int mt = 0; mt < 2; ++mt)
        #pragma unroll
        for (int nt = 0; nt < 4; ++nt)
            #pragma unroll
            for (int r = 0; r < 4; ++r) acc[mt][nt][r] = 0.f;

    #pragma unroll
    for (int ks = 0; ks < 2; ++ks) {
        const int kd = 4 * lg + 16 * ks;
        const int am = (lr & 7) << 2;
        const bf16x8 a0 = *(const bf16x8*)&qA[wv * 1024 + lr * 32 + (kd ^ am)];
        const bf16x8 a1 = *(const bf16x8*)&qA[wv * 1024 + (16 + lr) * 32 + (kd ^ am)];
        #pragma unroll
        for (int nt = 0; nt < 4; ++nt) {
            const bf16x8 b = *(const bf16x8*)&kvT[(16 * nt + lr) * 32 + (kd ^ am)];
            acc[0][nt] = __builtin_amdgcn_mfma_f32_16x16x32_bf16(a0, b, acc[0][nt],
                                                                 0, 0, 0);
            acc[1][nt] = __builtin_amdgcn_mfma_f32_16x16x32_bf16(a1, b, acc[1][nt],
                                                                 0, 0, 0);
        }
    }

    // ---- repack acc through per-wave LDS -> coalesced NT stores (barriered) ----
    float* oS = (float*)qA;
    #pragma unroll
    for (int mt = 0; mt < 2; ++mt) {
        __syncthreads();
        #pragma unroll
        for (int r = 0; r < 4; ++r) {
            const int row = 4 * lg + r;  // 0..15
            const float inv = 1.f / denomS[wv * 32 + mt * 16 + row];
            #pragma unroll
            for (int nt = 0; nt < 4; ++nt) {
                const int colp = (16 * nt + lr) ^ (lg << 4);
                oS[wv * 1024 + row * 64 + colp] = acc[mt][nt][r] * inv;
            }
        }
        __syncthreads();
        #pragma unroll
        for (int j = 0; j < 4; ++j) {
            const int row = 4 * j + lg;           // 0..15
            const int cb = lr * 4;
            const int colp = cb ^ ((row >> 2) << 4);
            const f32x4 o = *(const f32x4*)&oS[wv * 1024 + row * 64 + colp];
            float* orow = Ob + (size_t)(wv * 32 + mt * 16 + row) * DIM + cb;
            __builtin_nontemporal_store(o, (f32x4*)orow);
        }
    }
}

extern "C" void kernel_launch(void* const* d_in, const int* in_sizes, int n_in,
                              void* d_out, int out_size, void* d_ws, size_t ws_size,
                              hipStream_t stream) {
    const float* q = (const float*)d_in[0];
    const float* k = (const float*)d_in[1];
    const float* v = (const float*)d_in[2];
    float* out = (float*)d_out;
    float* ws = (float*)d_ws;

    const size_t partial_elems = (size_t)NPB * BH * KVELEM;
    const size_t finp_elems = (size_t)BH * KVO;
    const size_t need = (partial_elems + finp_elems) * sizeof(float);
    const size_t need_atomic = ((size_t)BH * KVELEM + finp_elems) * sizeof(float);

    dim3 blk(256);
    if (ws_size >= need) {
        float* partial = ws;
        float* finp = ws + partial_elems;
        hipLaunchKernelGGL((kv_mfma_kernel<false>), dim3(NPB, BH), blk, 0, stream,
                           k, v, partial);
        hipLaunchKernelGGL(reduce_pack_kernel, dim3(BH), blk, 0, stream,
                           partial, finp);
        hipLaunchKernelGGL(out_kernel, dim3(SEQ / 128, BH), blk, 0, stream,
                           q, finp, out);
    } else {
        float* fin = ws;                          // BH*KVELEM fp32 aggregate
        float* finp = ws + (size_t)BH * KVELEM;   // packed
        hipMemsetAsync(fin, 0, (size_t)BH * KVELEM * sizeof(float), stream);
        hipLaunchKernelGGL((kv_mfma_kernel<true>), dim3(NPB, BH), blk, 0, stream,
                           k, v, fin);
        hipLaunchKernelGGL(pack_kernel, dim3(BH), blk, 0, stream, fin, finp);
        hipLaunchKernelGGL(out_kernel, dim3(SEQ / 128, BH), blk, 0, stream,
                           q, finp, out);
    }
}

// Round 17
// 69.355 us; speedup vs baseline: 7.0261x; 1.1226x over previous
//
#include <hip/hip_runtime.h>

// LinearAttention fp32 [4,16,4096,64]: out = (Q' (K'^T V)) / (Q'.k_sum + eps), X' = elu(X)+1.
// R17 = R16 with reduce_pack re-parallelized: R16 collapsed the reducer to 64
// blocks (64 of 256 CUs, 160 chained loads/thread -> ~15-20us latency-bound);
// now dim3(4,BH)=256 blocks, each owning 16 d-rows: 1 f32x4/thread x 32 coalesced
// partial loads + packs its 512 dwords. Hot kernels identical to R13/R16.
// Pass 1 (kv_mfma): NT loads, single-phase, bf16 MFMA (K=128), 4 blocks/CU.
// Pass 1b (reduce_pack): fold 32 partials -> packed bf16 kvT + fp32 ksum.
// Pass 2 (out_kernel): Q' bf16 staged, kvT linear copy, 16x MFMA, fp32 denom,
//   barriered LDS repack -> coalesced NT stores.

#define EPS_LA 1e-6f

constexpr int BH = 64;
constexpr int SEQ = 4096;
constexpr int DIM = 64;
constexpr int KVELEM = DIM * DIM + DIM;  // 4160 fp32 (partial: kv + ksum)
constexpr int NPB = 32;                  // partial blocks per bh
constexpr int SCH = SEQ / NPB;           // 128 s-rows per block
constexpr int KVO = 2048 + 64;           // packed dwords/bh: bf16 kvT pairs + fp32 ksum

typedef short bf16x8 __attribute__((ext_vector_type(8)));
typedef float f32x4 __attribute__((ext_vector_type(4)));

__device__ __forceinline__ float elu1(float x) {
    return x > 0.f ? x + 1.f : __expf(x);
}
__device__ __forceinline__ f32x4 elu4v(f32x4 v) {
    v[0] = elu1(v[0]); v[1] = elu1(v[1]); v[2] = elu1(v[2]); v[3] = elu1(v[3]);
    return v;
}
__device__ __forceinline__ f32x4 ntld(const float* p) {
    return __builtin_nontemporal_load((const f32x4*)p);
}

// fp32 -> bf16 (RNE; inputs finite)
__device__ __forceinline__ unsigned int f2bf(float x) {
    unsigned int u = __float_as_uint(x);
    return (u + 0x7fffu + ((u >> 16) & 1u)) >> 16;
}
__device__ __forceinline__ unsigned int pack2bf(float lo, float hi) {
    return f2bf(lo) | (f2bf(hi) << 16);
}

// Pass-1 LDS swizzle: dword index into [64 rows][64 dword-cols]
__device__ __forceinline__ int swz(int d, int s2) {
    return d * 64 + (s2 ^ ((((d >> 1) ^ (d >> 2)) & 7) << 2));
}

template<bool ATOMIC>
__global__ __launch_bounds__(256, 4) void kv_mfma_kernel(
    const float* __restrict__ K, const float* __restrict__ V,
    float* __restrict__ dst) {
    const int bh = blockIdx.y;
    const int blk = blockIdx.x;
    const int t = threadIdx.x;
    const int w = t >> 6, l = t & 63;

    __shared__ unsigned int KT[64 * 64];  // 16 KB
    __shared__ unsigned int VT[64 * 64];  // 16 KB
    __shared__ float csumS[4][64];        // 1 KB

    const float* Kb = K + ((size_t)bh * SEQ + (size_t)blk * SCH) * DIM;
    const float* Vb = V + ((size_t)bh * SEQ + (size_t)blk * SCH) * DIM;

    const int c0 = (t & 15) * 4;
    const int pg = t >> 4;
    const int lg = l >> 4;
    const int lr = l & 15;

    // ---- issue ALL 16 non-temporal loads ----
    f32x4 kf[8], vf[8];
    #pragma unroll
    for (int i = 0; i < 4; ++i) {
        const int p = pg + 16 * i;
        kf[2 * i]     = ntld(Kb + (size_t)(2 * p) * DIM + c0);
        kf[2 * i + 1] = ntld(Kb + (size_t)(2 * p + 1) * DIM + c0);
    }
    #pragma unroll
    for (int i = 0; i < 4; ++i) {
        const int p = pg + 16 * i;
        vf[2 * i]     = ntld(Vb + (size_t)(2 * p) * DIM + c0);
        vf[2 * i + 1] = ntld(Vb + (size_t)(2 * p + 1) * DIM + c0);
    }

    // ---- elu + pack + transpose into LDS ----
    float cs0 = 0.f, cs1 = 0.f, cs2 = 0.f, cs3 = 0.f;
    #pragma unroll
    for (int i = 0; i < 4; ++i) {
        const int p = pg + 16 * i;
        const f32x4 ka = elu4v(kf[2 * i]);
        const f32x4 kb = elu4v(kf[2 * i + 1]);
        cs0 += ka[0] + kb[0]; cs1 += ka[1] + kb[1];
        cs2 += ka[2] + kb[2]; cs3 += ka[3] + kb[3];
        KT[swz(c0 + 0, p)] = pack2bf(ka[0], kb[0]);
        KT[swz(c0 + 1, p)] = pack2bf(ka[1], kb[1]);
        KT[swz(c0 + 2, p)] = pack2bf(ka[2], kb[2]);
        KT[swz(c0 + 3, p)] = pack2bf(ka[3], kb[3]);
        const f32x4 va = vf[2 * i], vb = vf[2 * i + 1];
        VT[swz(c0 + 0, p)] = pack2bf(va[0], vb[0]);
        VT[swz(c0 + 1, p)] = pack2bf(va[1], vb[1]);
        VT[swz(c0 + 2, p)] = pack2bf(va[2], vb[2]);
        VT[swz(c0 + 3, p)] = pack2bf(va[3], vb[3]);
    }

    cs0 += __shfl_xor(cs0, 16); cs0 += __shfl_xor(cs0, 32);
    cs1 += __shfl_xor(cs1, 16); cs1 += __shfl_xor(cs1, 32);
    cs2 += __shfl_xor(cs2, 16); cs2 += __shfl_xor(cs2, 32);
    cs3 += __shfl_xor(cs3, 16); cs3 += __shfl_xor(cs3, 32);
    if (l < 16) *(f32x4*)&csumS[w][l * 4] = f32x4{cs0, cs1, cs2, cs3};

    __syncthreads();  // the ONLY barrier

    // ---- MFMA: wave w owns e-cols [16w,16w+16); K=128 (4 steps of 32) ----
    f32x4 acc[4];
    #pragma unroll
    for (int m = 0; m < 4; ++m)
        #pragma unroll
        for (int r = 0; r < 4; ++r) acc[m][r] = 0.f;

    #pragma unroll
    for (int ks = 0; ks < 4; ++ks) {
        const int s2b = ks * 16 + lg * 4;
        const bf16x8 bfrag =
            *reinterpret_cast<const bf16x8*>(&VT[swz(16 * w + lr, s2b)]);
        #pragma unroll
        for (int m = 0; m < 4; ++m) {
            const bf16x8 afrag =
                *reinterpret_cast<const bf16x8*>(&KT[swz(16 * m + lr, s2b)]);
            acc[m] = __builtin_amdgcn_mfma_f32_16x16x32_bf16(afrag, bfrag, acc[m],
                                                             0, 0, 0);
        }
    }

    float* wout = ATOMIC ? dst + (size_t)bh * KVELEM
                         : dst + ((size_t)blk * BH + bh) * KVELEM;

    if (t < 64) {
        const float s = csumS[0][t] + csumS[1][t] + csumS[2][t] + csumS[3][t];
        if (ATOMIC) atomicAdd(&wout[DIM * DIM + t], s);
        else        wout[DIM * DIM + t] = s;
    }

    #pragma unroll
    for (int m = 0; m < 4; ++m) {
        #pragma unroll
        for (int r = 0; r < 4; ++r) {
            const int d = 16 * m + 4 * lg + r;
            const int e = 16 * w + lr;
            if (ATOMIC) atomicAdd(&wout[(size_t)d * DIM + e], acc[m][r]);
            else        wout[(size_t)d * DIM + e] = acc[m][r];
        }
    }
}

// Reduce + pack, parallel: dim3(4, BH). Block x owns d-rows [16x,16x+16)
// (= d-pairs [8x, 8x+8), floats [1024x, 1024x+1024)). 1 f32x4/thread over NPB
// partials (coalesced), then pack 512 dwords. Block x==0 also folds ksum.
__global__ __launch_bounds__(256) void reduce_pack_kernel(
    const float* __restrict__ partial, float* __restrict__ finp) {
    const int bh = blockIdx.y;
    const int x = blockIdx.x;   // 0..3
    const int t = threadIdx.x;
    __shared__ float red[1024];

    {
        f32x4 s = {0.f, 0.f, 0.f, 0.f};
        const size_t base = (size_t)x * 1024 + (size_t)t * 4;
        #pragma unroll 4
        for (int c = 0; c < NPB; ++c)
            s += *(const f32x4*)&partial[((size_t)c * BH + bh) * KVELEM + base];
        *(f32x4*)&red[t * 4] = s;
    }
    float ks = 0.f;
    if (x == 0 && t < 64) {
        #pragma unroll 4
        for (int c = 0; c < NPB; ++c)
            ks += partial[((size_t)c * BH + bh) * KVELEM + DIM * DIM + t];
    }
    __syncthreads();

    unsigned int* f = (unsigned int*)(finp + (size_t)bh * KVO);
    const int p_loc = t >> 5;          // 0..7 (local d-pair)
    const int p = x * 8 + p_loc;       // global d-pair
    const int e0 = (t & 31) * 2;
    #pragma unroll
    for (int j = 0; j < 2; ++j) {
        const int e = e0 + j;
        f[e * 32 + (p ^ ((e & 7) << 2))] =
            pack2bf(red[(size_t)(2 * p_loc) * DIM + e],
                    red[(size_t)(2 * p_loc + 1) * DIM + e]);
    }
    if (x == 0 && t < 64) ((float*)f)[2048 + t] = ks;
}

// Fallback pack (atomic path): fp32 aggregate -> packed fin, one block per bh.
__global__ __launch_bounds__(256) void pack_kernel(
    const float* __restrict__ fin, float* __restrict__ finp) {
    const int bh = blockIdx.x;
    const int t = threadIdx.x;
    __shared__ float red[KVELEM];
    #pragma unroll
    for (int i = 0; i < 5; ++i) {
        const int j4 = t + 256 * i;
        if (j4 < KVELEM / 4)
            *(f32x4*)&red[j4 * 4] = *(const f32x4*)&fin[(size_t)bh * KVELEM + j4 * 4];
    }
    __syncthreads();
    unsigned int* f = (unsigned int*)(finp + (size_t)bh * KVO);
    #pragma unroll
    for (int i = 0; i < 2; ++i) {
        const int p = (t >> 4) + 16 * i;
        const int e0 = (t & 15) * 4;
        #pragma unroll
        for (int j = 0; j < 4; ++j) {
            const int e = e0 + j;
            f[e * 32 + (p ^ ((e & 7) << 2))] =
                pack2bf(red[(size_t)(2 * p) * DIM + e],
                        red[(size_t)(2 * p + 1) * DIM + e]);
        }
    }
    if (t < 64) ((float*)f)[2048 + t] = red[DIM * DIM + t];
}

// Pass 2 (MFMA): block = 256 thr (4 waves); wave wv owns 32 q-rows.
// kvT copied linearly from packed fin; fp32 denom via shfl butterfly;
// acc repacked through per-wave LDS (barriered) -> coalesced NT f32x4 stores.
__global__ __launch_bounds__(256) void out_kernel(
    const float* __restrict__ Q, const float* __restrict__ finp,
    float* __restrict__ out) {
    const int bh = blockIdx.y;
    const int rb = blockIdx.x;  // 128-row block
    const int t = threadIdx.x;
    const int wv = t >> 6, l = t & 63;
    const int lr = l & 15, lg = l >> 4;

    __shared__ unsigned int qA[4 * 32 * 32];  // 16 KB: per-wave Q' bf16 [row][d-pair]
    __shared__ unsigned int kvT[64 * 32];     // 8 KB: kv^T bf16 (pre-packed)
    __shared__ float denomS[128];

    const unsigned int* fT = (const unsigned int*)(finp + (size_t)bh * KVO);
    const float* ksumF = (const float*)(fT + 2048);
    const float* Qb = Q + ((size_t)bh * SEQ + (size_t)rb * 128) * DIM;
    float* Ob = out + ((size_t)bh * SEQ + (size_t)rb * 128) * DIM;

    // ---- kvT staging: straight copy (already packed+swizzled by producer) ----
    #pragma unroll
    for (int i = 0; i < 2; ++i) {
        const int j4 = t + 256 * i;  // uint4 slot 0..511
        *(uint4*)&kvT[j4 * 4] = *(const uint4*)&fT[j4 * 4];
    }

    // ---- q staging (NT): elu, pack bf16, swizzle; fp32 denom partials ----
    const int c0 = lr * 4;
    const f32x4 ks4 = *(const f32x4*)(ksumF + c0);
    float pd[8];
    #pragma unroll
    for (int it = 0; it < 8; ++it) {
        const int row = it * 4 + lg;          // 0..31 within wave
        const f32x4 qv = elu4v(ntld(Qb + (size_t)(wv * 32 + row) * DIM + c0));
        pd[it] = qv[0] * ks4[0] + qv[1] * ks4[1] + qv[2] * ks4[2] + qv[3] * ks4[3];
        uint2 val;
        val.x = pack2bf(qv[0], qv[1]);
        val.y = pack2bf(qv[2], qv[3]);
        *(uint2*)&qA[wv * 1024 + row * 32 + ((2 * lr) ^ ((row & 7) << 2))] = val;
    }
    #pragma unroll
    for (int it = 0; it < 8; ++it) {
        float v = pd[it];
        v += __shfl_xor(v, 1); v += __shfl_xor(v, 2);
        v += __shfl_xor(v, 4); v += __shfl_xor(v, 8);
        if (lr == 0) denomS[wv * 32 + it * 4 + lg] = v + EPS_LA;
    }
    __syncthreads();

    // ---- MFMA: rows 16*mt+lr, cols 16*nt+lr, K=64 in 2 steps ----
    f32x4 acc[2][4];
    #pragma unroll
    for (int mt = 0; mt < 2; ++mt)
        #pragma unroll
        for (int nt = 0; nt < 4; ++nt)
            #pragma unroll
            for (int r = 0; r < 4; ++r) acc[mt][nt][r] = 0.f;

    #pragma unroll
    for (int ks = 0; ks < 2; ++ks) {
        const int kd = 4 * lg + 16 * ks;
        const int am = (lr & 7) << 2;
        const bf16x8 a0 = *(const bf16x8*)&qA[wv * 1024 + lr * 32 + (kd ^ am)];
        const bf16x8 a1 = *(const bf16x8*)&qA[wv * 1024 + (16 + lr) * 32 + (kd ^ am)];
        #pragma unroll
        for (int nt = 0; nt < 4; ++nt) {
            const bf16x8 b = *(const bf16x8*)&kvT[(16 * nt + lr) * 32 + (kd ^ am)];
            acc[0][nt] = __builtin_amdgcn_mfma_f32_16x16x32_bf16(a0, b, acc[0][nt],
                                                                 0, 0, 0);
            acc[1][nt] = __builtin_amdgcn_mfma_f32_16x16x32_bf16(a1, b, acc[1][nt],
                                                                 0, 0, 0);
        }
    }

    // ---- repack acc through per-wave LDS -> coalesced NT stores (barriered) ----
    float* oS = (float*)qA;
    #pragma unroll
    for (int mt = 0; mt < 2; ++mt) {
        __syncthreads();
        #pragma unroll
        for (int r = 0; r < 4; ++r) {
            const int row = 4 * lg + r;  // 0..15
            const float inv = 1.f / denomS[wv * 32 + mt * 16 + row];
            #pragma unroll
            for (int nt = 0; nt < 4; ++nt) {
                const int colp = (16 * nt + lr) ^ (lg << 4);
                oS[wv * 1024 + row * 64 + colp] = acc[mt][nt][r] * inv;
            }
        }
        __syncthreads();
        #pragma unroll
        for (int j = 0; j < 4; ++j) {
            const int row = 4 * j + lg;           // 0..15
            const int cb = lr * 4;
            const int colp = cb ^ ((row >> 2) << 4);
            const f32x4 o = *(const f32x4*)&oS[wv * 1024 + row * 64 + colp];
            float* orow = Ob + (size_t)(wv * 32 + mt * 16 + row) * DIM + cb;
            __builtin_nontemporal_store(o, (f32x4*)orow);
        }
    }
}

extern "C" void kernel_launch(void* const* d_in, const int* in_sizes, int n_in,
                              void* d_out, int out_size, void* d_ws, size_t ws_size,
                              hipStream_t stream) {
    const float* q = (const float*)d_in[0];
    const float* k = (const float*)d_in[1];
    const float* v = (const float*)d_in[2];
    float* out = (float*)d_out;
    float* ws = (float*)d_ws;

    const size_t partial_elems = (size_t)NPB * BH * KVELEM;
    const size_t finp_elems = (size_t)BH * KVO;
    const size_t need = (partial_elems + finp_elems) * sizeof(float);

    dim3 blk(256);
    if (ws_size >= need) {
        float* partial = ws;
        float* finp = ws + partial_elems;
        hipLaunchKernelGGL((kv_mfma_kernel<false>), dim3(NPB, BH), blk, 0, stream,
                           k, v, partial);
        hipLaunchKernelGGL(reduce_pack_kernel, dim3(4, BH), blk, 0, stream,
                           partial, finp);
        hipLaunchKernelGGL(out_kernel, dim3(SEQ / 128, BH), blk, 0, stream,
                           q, finp, out);
    } else {
        float* fin = ws;                          // BH*KVELEM fp32 aggregate
        float* finp = ws + (size_t)BH * KVELEM;   // packed
        hipMemsetAsync(fin, 0, (size_t)BH * KVELEM * sizeof(float), stream);
        hipLaunchKernelGGL((kv_mfma_kernel<true>), dim3(NPB, BH), blk, 0, stream,
                           k, v, fin);
        hipLaunchKernelGGL(pack_kernel, dim3(BH), blk, 0, stream, fin, finp);
        hipLaunchKernelGGL(out_kernel, dim3(SEQ / 128, BH), blk, 0, stream,
                           q, finp, out);
    }
}

// Round 18
// 69.288 us; speedup vs baseline: 7.0329x; 1.0010x over previous
//
#include <hip/hip_runtime.h>

// LinearAttention fp32 [4,16,4096,64]: out = (Q' (K'^T V)) / (Q'.k_sum + eps), X' = elu(X)+1.
// R18 = R17 with ONE change: kv_mfma __launch_bounds__(256,4) -> (256,2).
// Mechanism: at (256,4) the compiler allocated only ~56 VGPRs -> the 16 NT f32x4
// loads (64 VGPRs of destinations) were issued in 2 batches with 2 latency drains.
// (256,2) lets all 16 stay in flight (R10/R11 setting; never A/B'd separately from
// the R12 out-store coalescing). Everything else identical to R17.
// Pass 1 (kv_mfma): NT loads, single-phase, bf16 MFMA (K=128).
// Pass 1b (reduce_pack): dim3(4,BH), fold 32 partials -> packed bf16 kvT + fp32 ksum.
// Pass 2 (out_kernel): Q' bf16 staged, kvT linear copy, 16x MFMA, fp32 denom,
//   barriered LDS repack -> coalesced NT stores.

#define EPS_LA 1e-6f

constexpr int BH = 64;
constexpr int SEQ = 4096;
constexpr int DIM = 64;
constexpr int KVELEM = DIM * DIM + DIM;  // 4160 fp32 (partial: kv + ksum)
constexpr int NPB = 32;                  // partial blocks per bh
constexpr int SCH = SEQ / NPB;           // 128 s-rows per block
constexpr int KVO = 2048 + 64;           // packed dwords/bh: bf16 kvT pairs + fp32 ksum

typedef short bf16x8 __attribute__((ext_vector_type(8)));
typedef float f32x4 __attribute__((ext_vector_type(4)));

__device__ __forceinline__ float elu1(float x) {
    return x > 0.f ? x + 1.f : __expf(x);
}
__device__ __forceinline__ f32x4 elu4v(f32x4 v) {
    v[0] = elu1(v[0]); v[1] = elu1(v[1]); v[2] = elu1(v[2]); v[3] = elu1(v[3]);
    return v;
}
__device__ __forceinline__ f32x4 ntld(const float* p) {
    return __builtin_nontemporal_load((const f32x4*)p);
}

// fp32 -> bf16 (RNE; inputs finite)
__device__ __forceinline__ unsigned int f2bf(float x) {
    unsigned int u = __float_as_uint(x);
    return (u + 0x7fffu + ((u >> 16) & 1u)) >> 16;
}
__device__ __forceinline__ unsigned int pack2bf(float lo, float hi) {
    return f2bf(lo) | (f2bf(hi) << 16);
}

// Pass-1 LDS swizzle: dword index into [64 rows][64 dword-cols]
__device__ __forceinline__ int swz(int d, int s2) {
    return d * 64 + (s2 ^ ((((d >> 1) ^ (d >> 2)) & 7) << 2));
}

template<bool ATOMIC>
__global__ __launch_bounds__(256, 2) void kv_mfma_kernel(
    const float* __restrict__ K, const float* __restrict__ V,
    float* __restrict__ dst) {
    const int bh = blockIdx.y;
    const int blk = blockIdx.x;
    const int t = threadIdx.x;
    const int w = t >> 6, l = t & 63;

    __shared__ unsigned int KT[64 * 64];  // 16 KB
    __shared__ unsigned int VT[64 * 64];  // 16 KB
    __shared__ float csumS[4][64];        // 1 KB

    const float* Kb = K + ((size_t)bh * SEQ + (size_t)blk * SCH) * DIM;
    const float* Vb = V + ((size_t)bh * SEQ + (size_t)blk * SCH) * DIM;

    const int c0 = (t & 15) * 4;
    const int pg = t >> 4;
    const int lg = l >> 4;
    const int lr = l & 15;

    // ---- issue ALL 16 non-temporal loads (all in flight: (256,2) => VGPR room) ----
    f32x4 kf[8], vf[8];
    #pragma unroll
    for (int i = 0; i < 4; ++i) {
        const int p = pg + 16 * i;
        kf[2 * i]     = ntld(Kb + (size_t)(2 * p) * DIM + c0);
        kf[2 * i + 1] = ntld(Kb + (size_t)(2 * p + 1) * DIM + c0);
    }
    #pragma unroll
    for (int i = 0; i < 4; ++i) {
        const int p = pg + 16 * i;
        vf[2 * i]     = ntld(Vb + (size_t)(2 * p) * DIM + c0);
        vf[2 * i + 1] = ntld(Vb + (size_t)(2 * p + 1) * DIM + c0);
    }

    // ---- elu + pack + transpose into LDS ----
    float cs0 = 0.f, cs1 = 0.f, cs2 = 0.f, cs3 = 0.f;
    #pragma unroll
    for (int i = 0; i < 4; ++i) {
        const int p = pg + 16 * i;
        const f32x4 ka = elu4v(kf[2 * i]);
        const f32x4 kb = elu4v(kf[2 * i + 1]);
        cs0 += ka[0] + kb[0]; cs1 += ka[1] + kb[1];
        cs2 += ka[2] + kb[2]; cs3 += ka[3] + kb[3];
        KT[swz(c0 + 0, p)] = pack2bf(ka[0], kb[0]);
        KT[swz(c0 + 1, p)] = pack2bf(ka[1], kb[1]);
        KT[swz(c0 + 2, p)] = pack2bf(ka[2], kb[2]);
        KT[swz(c0 + 3, p)] = pack2bf(ka[3], kb[3]);
        const f32x4 va = vf[2 * i], vb = vf[2 * i + 1];
        VT[swz(c0 + 0, p)] = pack2bf(va[0], vb[0]);
        VT[swz(c0 + 1, p)] = pack2bf(va[1], vb[1]);
        VT[swz(c0 + 2, p)] = pack2bf(va[2], vb[2]);
        VT[swz(c0 + 3, p)] = pack2bf(va[3], vb[3]);
    }

    cs0 += __shfl_xor(cs0, 16); cs0 += __shfl_xor(cs0, 32);
    cs1 += __shfl_xor(cs1, 16); cs1 += __shfl_xor(cs1, 32);
    cs2 += __shfl_xor(cs2, 16); cs2 += __shfl_xor(cs2, 32);
    cs3 += __shfl_xor(cs3, 16); cs3 += __shfl_xor(cs3, 32);
    if (l < 16) *(f32x4*)&csumS[w][l * 4] = f32x4{cs0, cs1, cs2, cs3};

    __syncthreads();  // the ONLY barrier

    // ---- MFMA: wave w owns e-cols [16w,16w+16); K=128 (4 steps of 32) ----
    f32x4 acc[4];
    #pragma unroll
    for (int m = 0; m < 4; ++m)
        #pragma unroll
        for (int r = 0; r < 4; ++r) acc[m][r] = 0.f;

    #pragma unroll
    for (int ks = 0; ks < 4; ++ks) {
        const int s2b = ks * 16 + lg * 4;
        const bf16x8 bfrag =
            *reinterpret_cast<const bf16x8*>(&VT[swz(16 * w + lr, s2b)]);
        #pragma unroll
        for (int m = 0; m < 4; ++m) {
            const bf16x8 afrag =
                *reinterpret_cast<const bf16x8*>(&KT[swz(16 * m + lr, s2b)]);
            acc[m] = __builtin_amdgcn_mfma_f32_16x16x32_bf16(afrag, bfrag, acc[m],
                                                             0, 0, 0);
        }
    }

    float* wout = ATOMIC ? dst + (size_t)bh * KVELEM
                         : dst + ((size_t)blk * BH + bh) * KVELEM;

    if (t < 64) {
        const float s = csumS[0][t] + csumS[1][t] + csumS[2][t] + csumS[3][t];
        if (ATOMIC) atomicAdd(&wout[DIM * DIM + t], s);
        else        wout[DIM * DIM + t] = s;
    }

    #pragma unroll
    for (int m = 0; m < 4; ++m) {
        #pragma unroll
        for (int r = 0; r < 4; ++r) {
            const int d = 16 * m + 4 * lg + r;
            const int e = 16 * w + lr;
            if (ATOMIC) atomicAdd(&wout[(size_t)d * DIM + e], acc[m][r]);
            else        wout[(size_t)d * DIM + e] = acc[m][r];
        }
    }
}

// Reduce + pack, parallel: dim3(4, BH). Block x owns d-rows [16x,16x+16)
// (= d-pairs [8x, 8x+8), floats [1024x, 1024x+1024)). 1 f32x4/thread over NPB
// partials (coalesced), then pack 512 dwords. Block x==0 also folds ksum.
__global__ __launch_bounds__(256) void reduce_pack_kernel(
    const float* __restrict__ partial, float* __restrict__ finp) {
    const int bh = blockIdx.y;
    const int x = blockIdx.x;   // 0..3
    const int t = threadIdx.x;
    __shared__ float red[1024];

    {
        f32x4 s = {0.f, 0.f, 0.f, 0.f};
        const size_t base = (size_t)x * 1024 + (size_t)t * 4;
        #pragma unroll 4
        for (int c = 0; c < NPB; ++c)
            s += *(const f32x4*)&partial[((size_t)c * BH + bh) * KVELEM + base];
        *(f32x4*)&red[t * 4] = s;
    }
    float ks = 0.f;
    if (x == 0 && t < 64) {
        #pragma unroll 4
        for (int c = 0; c < NPB; ++c)
            ks += partial[((size_t)c * BH + bh) * KVELEM + DIM * DIM + t];
    }
    __syncthreads();

    unsigned int* f = (unsigned int*)(finp + (size_t)bh * KVO);
    const int p_loc = t >> 5;          // 0..7 (local d-pair)
    const int p = x * 8 + p_loc;       // global d-pair
    const int e0 = (t & 31) * 2;
    #pragma unroll
    for (int j = 0; j < 2; ++j) {
        const int e = e0 + j;
        f[e * 32 + (p ^ ((e & 7) << 2))] =
            pack2bf(red[(size_t)(2 * p_loc) * DIM + e],
                    red[(size_t)(2 * p_loc + 1) * DIM + e]);
    }
    if (x == 0 && t < 64) ((float*)f)[2048 + t] = ks;
}

// Fallback pack (atomic path): fp32 aggregate -> packed fin, one block per bh.
__global__ __launch_bounds__(256) void pack_kernel(
    const float* __restrict__ fin, float* __restrict__ finp) {
    const int bh = blockIdx.x;
    const int t = threadIdx.x;
    __shared__ float red[KVELEM];
    #pragma unroll
    for (int i = 0; i < 5; ++i) {
        const int j4 = t + 256 * i;
        if (j4 < KVELEM / 4)
            *(f32x4*)&red[j4 * 4] = *(const f32x4*)&fin[(size_t)bh * KVELEM + j4 * 4];
    }
    __syncthreads();
    unsigned int* f = (unsigned int*)(finp + (size_t)bh * KVO);
    #pragma unroll
    for (int i = 0; i < 2; ++i) {
        const int p = (t >> 4) + 16 * i;
        const int e0 = (t & 15) * 4;
        #pragma unroll
        for (int j = 0; j < 4; ++j) {
            const int e = e0 + j;
            f[e * 32 + (p ^ ((e & 7) << 2))] =
                pack2bf(red[(size_t)(2 * p) * DIM + e],
                        red[(size_t)(2 * p + 1) * DIM + e]);
        }
    }
    if (t < 64) ((float*)f)[2048 + t] = red[DIM * DIM + t];
}

// Pass 2 (MFMA): block = 256 thr (4 waves); wave wv owns 32 q-rows.
// kvT copied linearly from packed fin; fp32 denom via shfl butterfly;
// acc repacked through per-wave LDS (barriered) -> coalesced NT f32x4 stores.
__global__ __launch_bounds__(256) void out_kernel(
    const float* __restrict__ Q, const float* __restrict__ finp,
    float* __restrict__ out) {
    const int bh = blockIdx.y;
    const int rb = blockIdx.x;  // 128-row block
    const int t = threadIdx.x;
    const int wv = t >> 6, l = t & 63;
    const int lr = l & 15, lg = l >> 4;

    __shared__ unsigned int qA[4 * 32 * 32];  // 16 KB: per-wave Q' bf16 [row][d-pair]
    __shared__ unsigned int kvT[64 * 32];     // 8 KB: kv^T bf16 (pre-packed)
    __shared__ float denomS[128];

    const unsigned int* fT = (const unsigned int*)(finp + (size_t)bh * KVO);
    const float* ksumF = (const float*)(fT + 2048);
    const float* Qb = Q + ((size_t)bh * SEQ + (size_t)rb * 128) * DIM;
    float* Ob = out + ((size_t)bh * SEQ + (size_t)rb * 128) * DIM;

    // ---- kvT staging: straight copy (already packed+swizzled by producer) ----
    #pragma unroll
    for (int i = 0; i < 2; ++i) {
        const int j4 = t + 256 * i;  // uint4 slot 0..511
        *(uint4*)&kvT[j4 * 4] = *(const uint4*)&fT[j4 * 4];
    }

    // ---- q staging (NT): elu, pack bf16, swizzle; fp32 denom partials ----
    const int c0 = lr * 4;
    const f32x4 ks4 = *(const f32x4*)(ksumF + c0);
    float pd[8];
    #pragma unroll
    for (int it = 0; it < 8; ++it) {
        const int row = it * 4 + lg;          // 0..31 within wave
        const f32x4 qv = elu4v(ntld(Qb + (size_t)(wv * 32 + row) * DIM + c0));
        pd[it] = qv[0] * ks4[0] + qv[1] * ks4[1] + qv[2] * ks4[2] + qv[3] * ks4[3];
        uint2 val;
        val.x = pack2bf(qv[0], qv[1]);
        val.y = pack2bf(qv[2], qv[3]);
        *(uint2*)&qA[wv * 1024 + row * 32 + ((2 * lr) ^ ((row & 7) << 2))] = val;
    }
    #pragma unroll
    for (int it = 0; it < 8; ++it) {
        float v = pd[it];
        v += __shfl_xor(v, 1); v += __shfl_xor(v, 2);
        v += __shfl_xor(v, 4); v += __shfl_xor(v, 8);
        if (lr == 0) denomS[wv * 32 + it * 4 + lg] = v + EPS_LA;
    }
    __syncthreads();

    // ---- MFMA: rows 16*mt+lr, cols 16*nt+lr, K=64 in 2 steps ----
    f32x4 acc[2][4];
    #pragma unroll
    for (int mt = 0; mt < 2; ++mt)
        #pragma unroll
        for (int nt = 0; nt < 4; ++nt)
            #pragma unroll
            for (int r = 0; r < 4; ++r) acc[mt][nt][r] = 0.f;

    #pragma unroll
    for (int ks = 0; ks < 2; ++ks) {
        const int kd = 4 * lg + 16 * ks;
        const int am = (lr & 7) << 2;
        const bf16x8 a0 = *(const bf16x8*)&qA[wv * 1024 + lr * 32 + (kd ^ am)];
        const bf16x8 a1 = *(const bf16x8*)&qA[wv * 1024 + (16 + lr) * 32 + (kd ^ am)];
        #pragma unroll
        for (int nt = 0; nt < 4; ++nt) {
            const bf16x8 b = *(const bf16x8*)&kvT[(16 * nt + lr) * 32 + (kd ^ am)];
            acc[0][nt] = __builtin_amdgcn_mfma_f32_16x16x32_bf16(a0, b, acc[0][nt],
                                                                 0, 0, 0);
            acc[1][nt] = __builtin_amdgcn_mfma_f32_16x16x32_bf16(a1, b, acc[1][nt],
                                                                 0, 0, 0);
        }
    }

    // ---- repack acc through per-wave LDS -> coalesced NT stores (barriered) ----
    float* oS = (float*)qA;
    #pragma unroll
    for (int mt = 0; mt < 2; ++mt) {
        __syncthreads();
        #pragma unroll
        for (int r = 0; r < 4; ++r) {
            const int row = 4 * lg + r;  // 0..15
            const float inv = 1.f / denomS[wv * 32 + mt * 16 + row];
            #pragma unroll
            for (int nt = 0; nt < 4; ++nt) {
                const int colp = (16 * nt + lr) ^ (lg << 4);
                oS[wv * 1024 + row * 64 + colp] = acc[mt][nt][r] * inv;
            }
        }
        __syncthreads();
        #pragma unroll
        for (int j = 0; j < 4; ++j) {
            const int row = 4 * j + lg;           // 0..15
            const int cb = lr * 4;
            const int colp = cb ^ ((row >> 2) << 4);
            const f32x4 o = *(const f32x4*)&oS[wv * 1024 + row * 64 + colp];
            float* orow = Ob + (size_t)(wv * 32 + mt * 16 + row) * DIM + cb;
            __builtin_nontemporal_store(o, (f32x4*)orow);
        }
    }
}

extern "C" void kernel_launch(void* const* d_in, const int* in_sizes, int n_in,
                              void* d_out, int out_size, void* d_ws, size_t ws_size,
                              hipStream_t stream) {
    const float* q = (const float*)d_in[0];
    const float* k = (const float*)d_in[1];
    const float* v = (const float*)d_in[2];
    float* out = (float*)d_out;
    float* ws = (float*)d_ws;

    const size_t partial_elems = (size_t)NPB * BH * KVELEM;
    const size_t finp_elems = (size_t)BH * KVO;
    const size_t need = (partial_elems + finp_elems) * sizeof(float);

    dim3 blk(256);
    if (ws_size >= need) {
        float* partial = ws;
        float* finp = ws + partial_elems;
        hipLaunchKernelGGL((kv_mfma_kernel<false>), dim3(NPB, BH), blk, 0, stream,
                           k, v, partial);
        hipLaunchKernelGGL(reduce_pack_kernel, dim3(4, BH), blk, 0, stream,
                           partial, finp);
        hipLaunchKernelGGL(out_kernel, dim3(SEQ / 128, BH), blk, 0, stream,
                           q, finp, out);
    } else {
        float* fin = ws;                          // BH*KVELEM fp32 aggregate
        float* finp = ws + (size_t)BH * KVELEM;   // packed
        hipMemsetAsync(fin, 0, (size_t)BH * KVELEM * sizeof(float), stream);
        hipLaunchKernelGGL((kv_mfma_kernel<true>), dim3(NPB, BH), blk, 0, stream,
                           k, v, fin);
        hipLaunchKernelGGL(pack_kernel, dim3(BH), blk, 0, stream, fin, finp);
        hipLaunchKernelGGL(out_kernel, dim3(SEQ / 128, BH), blk, 0, stream,
                           q, finp, out);
    }
}